// Round 5
// baseline (408.159 us; speedup 1.0000x reference)
//
#include <hip/hip_runtime.h>

#define FP8_MAX 448.0f
#define EPSF 1e-12f

#define BM 256
#define BN 256
#define BK 64

typedef __attribute__((ext_vector_type(8))) _Float16 half8;
typedef __attribute__((ext_vector_type(4))) float floatx4;

#define VMCNT(n) asm volatile("s_waitcnt vmcnt(" #n ")" ::: "memory")
#define LGKM(n) asm volatile("s_waitcnt lgkmcnt(" #n ")" ::: "memory")

__device__ inline void async_copy16(const void* gp, void* lp) {
  __builtin_amdgcn_global_load_lds(
      (const __attribute__((address_space(1))) unsigned int*)gp,
      (__attribute__((address_space(3))) unsigned int*)lp,
      16, 0, 0);
}

// ---------------- absmax reduction: out = max(|in|) as uint bits ----------
__global__ void absmax_kernel(const float* __restrict__ in, int n4,
                              unsigned* __restrict__ out) {
  int tid = blockIdx.x * blockDim.x + threadIdx.x;
  int stride = gridDim.x * blockDim.x;
  const float4* in4 = (const float4*)in;
  float m = 0.f;
  for (int i = tid; i < n4; i += stride) {
    float4 v = in4[i];
    m = fmaxf(m, fmaxf(fmaxf(fabsf(v.x), fabsf(v.y)),
                       fmaxf(fabsf(v.z), fabsf(v.w))));
  }
  for (int off = 32; off > 0; off >>= 1)
    m = fmaxf(m, __shfl_down(m, off, 64));
  __shared__ float smax[4];
  int lane = threadIdx.x & 63, w = threadIdx.x >> 6;
  if (lane == 0) smax[w] = m;
  __syncthreads();
  if (threadIdx.x == 0) {
    float b = fmaxf(fmaxf(smax[0], smax[1]), fmaxf(smax[2], smax[3]));
    atomicMax(out, __float_as_uint(b));  // nonneg float bits: uint-monotonic
  }
}

// ---------------- quantize: fp32 -> fp16 integers in [-448,448] -----------
__global__ void quant_kernel(const float* __restrict__ in,
                             _Float16* __restrict__ out, int n8,
                             const unsigned* __restrict__ amax_bits) {
  const float scale = fmaxf(__uint_as_float(*amax_bits) / FP8_MAX, EPSF);
  int tid = blockIdx.x * blockDim.x + threadIdx.x;
  int stride = gridDim.x * blockDim.x;
  const float4* in4 = (const float4*)in;
  half8* out8 = (half8*)out;
  for (int i = tid; i < n8; i += stride) {
    float4 a = in4[2 * i], b = in4[2 * i + 1];
    half8 h;
    h[0] = (_Float16)rintf(fminf(fmaxf(a.x / scale, -FP8_MAX), FP8_MAX));
    h[1] = (_Float16)rintf(fminf(fmaxf(a.y / scale, -FP8_MAX), FP8_MAX));
    h[2] = (_Float16)rintf(fminf(fmaxf(a.z / scale, -FP8_MAX), FP8_MAX));
    h[3] = (_Float16)rintf(fminf(fmaxf(a.w / scale, -FP8_MAX), FP8_MAX));
    h[4] = (_Float16)rintf(fminf(fmaxf(b.x / scale, -FP8_MAX), FP8_MAX));
    h[5] = (_Float16)rintf(fminf(fmaxf(b.y / scale, -FP8_MAX), FP8_MAX));
    h[6] = (_Float16)rintf(fminf(fmaxf(b.z / scale, -FP8_MAX), FP8_MAX));
    h[7] = (_Float16)rintf(fminf(fmaxf(b.w / scale, -FP8_MAX), FP8_MAX));
    out8[i] = h;
  }
}

// -------- 256x256 m201-style 8-phase/2-tile NT GEMM (T1..T5) --------------
// 8 waves (2M x 4N). Quadrant fragment mapping (region-aligned):
//   aL: A rows wr*64+m*16        (A half0)   aH: 128+wr*64+m*16   (A half1)
//   bL: B rows wc*32+n*16        (B half0)   bH: 128+wc*32+n*16   (B half1)
// Per tile, phases read 12/4/8/0 with reuse: P1 aL+bL, P2 bH, P3 aH, P4 -.
// Iter (t even): tile t in buf0 (P1-4), tile t+1 in buf1 (P5-8).
// Stage 1 half-tile/phase: P1 A(t+1)h1, P2 A(t+2)h0, P3 B(t+2)h0,
//   P4 B(t+2)h1, P5 A(t+2)h1, P6 A(t+3)h0, P7 B(t+3)h0, P8 B(t+3)h1.
// vmcnt(6) at P4/P8 end leaves exactly 3 newest half-tiles in flight.
__global__ __launch_bounds__(512, 2) void gemm8_kernel(
    const _Float16* __restrict__ A,  // [M][K]
    const _Float16* __restrict__ B,  // [N][K]
    const float* __restrict__ bias, const unsigned* __restrict__ amax,
    float* __restrict__ C,  // [M][N]
    int M, int N, int K) {
  __shared__ __align__(16) _Float16 As[2][BM * BK];
  __shared__ __align__(16) _Float16 Bs[2][BN * BK];

  const int tid = threadIdx.x;
  const int w = tid >> 6;
  const int lane = tid & 63;
  const int wr = w >> 2;  // 0..1
  const int wc = w & 3;   // 0..3

  // XCD-aware block swizzle (gridDim.x divisible by 8)
  const int nwg = gridDim.x;
  const int cpx = nwg >> 3;
  const int swz = (blockIdx.x & 7) * cpx + (blockIdx.x >> 3);
  const int nbn = N / BN;
  const int bm = swz / nbn;
  const int bn = swz % nbn;

  const _Float16* Ab = A + (size_t)bm * BM * K;
  const _Float16* Bb = B + (size_t)bn * BN * K;

  // staging: lane l covers LDS row +(l>>3), LDS granule l&7; fetch DATA
  // granule (l&7)^((l>>3)&7) so reader-side XOR sees linear data.
  const int srow8 = w * 8 + (lane >> 3);
  const int gd8 = ((lane & 7) ^ ((lane >> 3) & 7)) * 8;
  const _Float16* Ag = Ab + (size_t)srow8 * K + gd8;
  const _Float16* Bg = Bb + (size_t)srow8 * K + gd8;

  auto stageA = [&](int kt, int h) {  // half h: rows h*128..h*128+127
#pragma unroll
    for (int r = 2 * h; r < 2 * h + 2; ++r)
      async_copy16(Ag + (size_t)(r * 64) * K + kt * BK,
                   (void*)&As[kt & 1][(r * 64 + w * 8) * BK]);
  };
  auto stageB = [&](int kt, int h) {
#pragma unroll
    for (int r = 2 * h; r < 2 * h + 2; ++r)
      async_copy16(Bg + (size_t)(r * 64) * K + kt * BK,
                   (void*)&Bs[kt & 1][(r * 64 + w * 8) * BK]);
  };

  // swizzled ds_read geometry: row = base + (lane&15), granule kk*4+(lane>>4),
  // swizzled granule = g ^ (row&7). All bases are multiples of 8 -> row&7=lr&7.
  const int lr = lane & 15;
  const int hi = lane >> 4;
  const int g0 = (hi ^ (lr & 7)) * 8;        // kk0
  const int g1 = ((4 + hi) ^ (lr & 7)) * 8;  // kk1
  const int aoffL = (wr * 64 + lr) * BK;
  const int aoffH = (128 + wr * 64 + lr) * BK;
  const int boffL = (wc * 32 + lr) * BK;
  const int boffH = (128 + wc * 32 + lr) * BK;

  half8 aL[4][2], aH[4][2], bL[2][2], bH[2][2];
  floatx4 acc[8][4] = {};
  const int nt = K / BK;

  // ---- prologue: tile0 (4 halves) + tile1 minus A-h1; vmcnt(6) leaves the
  // 3 newest half-tiles {A(1)h0,B(1)h0,B(1)h1} in flight == steady invariant.
  stageA(0, 0); stageB(0, 0); stageB(0, 1); stageA(0, 1);
  stageA(1, 0); stageB(1, 0); stageB(1, 1);
  VMCNT(6);
  __builtin_amdgcn_s_barrier();

  for (int t = 0; t < nt; t += 2) {
    const _Float16* As0 = &As[0][0];
    const _Float16* Bs0 = &Bs[0][0];
    const _Float16* As1 = &As[1][0];
    const _Float16* Bs1 = &Bs[1][0];

    // ===== P1: read aL+bL(tile t); stage A(t+1)h1; MFMA Q1 = mL x nL
#pragma unroll
    for (int m = 0; m < 4; ++m) {
      aL[m][0] = *(const half8*)&As0[aoffL + m * 16 * BK + g0];
      aL[m][1] = *(const half8*)&As0[aoffL + m * 16 * BK + g1];
    }
#pragma unroll
    for (int n = 0; n < 2; ++n) {
      bL[n][0] = *(const half8*)&Bs0[boffL + n * 16 * BK + g0];
      bL[n][1] = *(const half8*)&Bs0[boffL + n * 16 * BK + g1];
    }
    stageA(t + 1, 1);
    LGKM(8);
    __builtin_amdgcn_s_barrier();
    LGKM(0);
    __builtin_amdgcn_s_setprio(1);
#pragma unroll
    for (int m = 0; m < 4; ++m)
#pragma unroll
      for (int n = 0; n < 2; ++n)
#pragma unroll
        for (int kk = 0; kk < 2; ++kk)
          acc[m][n] = __builtin_amdgcn_mfma_f32_16x16x32_f16(
              aL[m][kk], bL[n][kk], acc[m][n], 0, 0, 0);
    __builtin_amdgcn_s_setprio(0);
    __builtin_amdgcn_s_barrier();

    // ===== P2: read bH; stage A(t+2)h0; MFMA Q2 = mL x nH
#pragma unroll
    for (int n = 0; n < 2; ++n) {
      bH[n][0] = *(const half8*)&Bs0[boffH + n * 16 * BK + g0];
      bH[n][1] = *(const half8*)&Bs0[boffH + n * 16 * BK + g1];
    }
    if (t + 2 < nt) stageA(t + 2, 0);
    __builtin_amdgcn_s_barrier();
    LGKM(0);
    __builtin_amdgcn_s_setprio(1);
#pragma unroll
    for (int m = 0; m < 4; ++m)
#pragma unroll
      for (int n = 0; n < 2; ++n)
#pragma unroll
        for (int kk = 0; kk < 2; ++kk)
          acc[m][2 + n] = __builtin_amdgcn_mfma_f32_16x16x32_f16(
              aL[m][kk], bH[n][kk], acc[m][2 + n], 0, 0, 0);
    __builtin_amdgcn_s_setprio(0);
    __builtin_amdgcn_s_barrier();

    // ===== P3: read aH; stage B(t+2)h0; MFMA Q3 = mH x nL
#pragma unroll
    for (int m = 0; m < 4; ++m) {
      aH[m][0] = *(const half8*)&As0[aoffH + m * 16 * BK + g0];
      aH[m][1] = *(const half8*)&As0[aoffH + m * 16 * BK + g1];
    }
    if (t + 2 < nt) stageB(t + 2, 0);
    __builtin_amdgcn_s_barrier();
    LGKM(0);
    __builtin_amdgcn_s_setprio(1);
#pragma unroll
    for (int m = 0; m < 4; ++m)
#pragma unroll
      for (int n = 0; n < 2; ++n)
#pragma unroll
        for (int kk = 0; kk < 2; ++kk)
          acc[4 + m][n] = __builtin_amdgcn_mfma_f32_16x16x32_f16(
              aH[m][kk], bL[n][kk], acc[4 + m][n], 0, 0, 0);
    __builtin_amdgcn_s_setprio(0);
    __builtin_amdgcn_s_barrier();

    // ===== P4: stage B(t+2)h1; MFMA Q4 = mH x nH; vmcnt(6)
    if (t + 2 < nt) stageB(t + 2, 1);
    __builtin_amdgcn_s_barrier();
    __builtin_amdgcn_s_setprio(1);
#pragma unroll
    for (int m = 0; m < 4; ++m)
#pragma unroll
      for (int n = 0; n < 2; ++n)
#pragma unroll
        for (int kk = 0; kk < 2; ++kk)
          acc[4 + m][2 + n] = __builtin_amdgcn_mfma_f32_16x16x32_f16(
              aH[m][kk], bH[n][kk], acc[4 + m][2 + n], 0, 0, 0);
    __builtin_amdgcn_s_setprio(0);
    if (t + 2 < nt) { VMCNT(6); } else { VMCNT(0); }
    __builtin_amdgcn_s_barrier();

    // ===== P5: read aL+bL(tile t+1); stage A(t+2)h1; MFMA Q1
#pragma unroll
    for (int m = 0; m < 4; ++m) {
      aL[m][0] = *(const half8*)&As1[aoffL + m * 16 * BK + g0];
      aL[m][1] = *(const half8*)&As1[aoffL + m * 16 * BK + g1];
    }
#pragma unroll
    for (int n = 0; n < 2; ++n) {
      bL[n][0] = *(const half8*)&Bs1[boffL + n * 16 * BK + g0];
      bL[n][1] = *(const half8*)&Bs1[boffL + n * 16 * BK + g1];
    }
    if (t + 2 < nt) stageA(t + 2, 1);
    LGKM(8);
    __builtin_amdgcn_s_barrier();
    LGKM(0);
    __builtin_amdgcn_s_setprio(1);
#pragma unroll
    for (int m = 0; m < 4; ++m)
#pragma unroll
      for (int n = 0; n < 2; ++n)
#pragma unroll
        for (int kk = 0; kk < 2; ++kk)
          acc[m][n] = __builtin_amdgcn_mfma_f32_16x16x32_f16(
              aL[m][kk], bL[n][kk], acc[m][n], 0, 0, 0);
    __builtin_amdgcn_s_setprio(0);
    __builtin_amdgcn_s_barrier();

    // ===== P6: read bH; stage A(t+3)h0; MFMA Q2
#pragma unroll
    for (int n = 0; n < 2; ++n) {
      bH[n][0] = *(const half8*)&Bs1[boffH + n * 16 * BK + g0];
      bH[n][1] = *(const half8*)&Bs1[boffH + n * 16 * BK + g1];
    }
    if (t + 3 < nt) stageA(t + 3, 0);
    __builtin_amdgcn_s_barrier();
    LGKM(0);
    __builtin_amdgcn_s_setprio(1);
#pragma unroll
    for (int m = 0; m < 4; ++m)
#pragma unroll
      for (int n = 0; n < 2; ++n)
#pragma unroll
        for (int kk = 0; kk < 2; ++kk)
          acc[m][2 + n] = __builtin_amdgcn_mfma_f32_16x16x32_f16(
              aL[m][kk], bH[n][kk], acc[m][2 + n], 0, 0, 0);
    __builtin_amdgcn_s_setprio(0);
    __builtin_amdgcn_s_barrier();

    // ===== P7: read aH; stage B(t+3)h0; MFMA Q3
#pragma unroll
    for (int m = 0; m < 4; ++m) {
      aH[m][0] = *(const half8*)&As1[aoffH + m * 16 * BK + g0];
      aH[m][1] = *(const half8*)&As1[aoffH + m * 16 * BK + g1];
    }
    if (t + 3 < nt) stageB(t + 3, 0);
    __builtin_amdgcn_s_barrier();
    LGKM(0);
    __builtin_amdgcn_s_setprio(1);
#pragma unroll
    for (int m = 0; m < 4; ++m)
#pragma unroll
      for (int n = 0; n < 2; ++n)
#pragma unroll
        for (int kk = 0; kk < 2; ++kk)
          acc[4 + m][n] = __builtin_amdgcn_mfma_f32_16x16x32_f16(
              aH[m][kk], bL[n][kk], acc[4 + m][n], 0, 0, 0);
    __builtin_amdgcn_s_setprio(0);
    __builtin_amdgcn_s_barrier();

    // ===== P8: stage B(t+3)h1; MFMA Q4; vmcnt(6)
    if (t + 3 < nt) stageB(t + 3, 1);
    __builtin_amdgcn_s_barrier();
    __builtin_amdgcn_s_setprio(1);
#pragma unroll
    for (int m = 0; m < 4; ++m)
#pragma unroll
      for (int n = 0; n < 2; ++n)
#pragma unroll
        for (int kk = 0; kk < 2; ++kk)
          acc[4 + m][2 + n] = __builtin_amdgcn_mfma_f32_16x16x32_f16(
              aH[m][kk], bH[n][kk], acc[4 + m][2 + n], 0, 0, 0);
    __builtin_amdgcn_s_setprio(0);
    if (t + 3 < nt) { VMCNT(6); } else { VMCNT(0); }
    __builtin_amdgcn_s_barrier();
  }

  // ---- epilogue: dequant + bias
  const float sx = fmaxf(__uint_as_float(amax[0]) / FP8_MAX, EPSF);
  const float sw = fmaxf(__uint_as_float(amax[1]) / FP8_MAX, EPSF);
  const float s = sx * sw;

  // row(m,r) = bm*256 + (m>>2)*128 + wr*64 + (m&3)*16 + hi*4 + r
  // col(n)   = bn*256 + (n>>1)*128 + wc*32 + (n&1)*16 + lr
  float bv[4];
#pragma unroll
  for (int n = 0; n < 4; ++n)
    bv[n] = bias[bn * BN + (n >> 1) * 128 + wc * 32 + (n & 1) * 16 + lr];

#pragma unroll
  for (int m = 0; m < 8; ++m) {
#pragma unroll
    for (int n = 0; n < 4; ++n) {
      const int row = bm * BM + (m >> 2) * 128 + wr * 64 + (m & 3) * 16 + hi * 4;
      const int col = bn * BN + (n >> 1) * 128 + wc * 32 + (n & 1) * 16 + lr;
      const size_t base = (size_t)row * N + col;
#pragma unroll
      for (int r = 0; r < 4; ++r)
        C[base + (size_t)r * N] = acc[m][n][r] * s + bv[n];
    }
  }
}

extern "C" void kernel_launch(void* const* d_in, const int* in_sizes, int n_in,
                              void* d_out, int out_size, void* d_ws,
                              size_t ws_size, hipStream_t stream) {
  const float* x = (const float*)d_in[0];
  const float* wgt = (const float*)d_in[1];
  const float* bias = (const float*)d_in[2];
  float* out = (float*)d_out;

  const int N = in_sizes[2];      // out features (4096)
  const int K = in_sizes[1] / N;  // in features (4096)
  const int M = in_sizes[0] / K;  // rows (8192)

  unsigned* amax = (unsigned*)d_ws;
  _Float16* xq = (_Float16*)((char*)d_ws + 256);
  _Float16* wq =
      (_Float16*)((char*)d_ws + 256 + (size_t)M * K * sizeof(_Float16));

  hipMemsetAsync(d_ws, 0, 8, stream);
  absmax_kernel<<<2048, 256, 0, stream>>>(x, M * K / 4, amax);
  absmax_kernel<<<1024, 256, 0, stream>>>(wgt, N * K / 4, amax + 1);
  quant_kernel<<<2048, 256, 0, stream>>>(x, xq, M * K / 8, amax);
  quant_kernel<<<1024, 256, 0, stream>>>(wgt, wq, N * K / 8, amax + 1);

  gemm8_kernel<<<dim3((M / BM) * (N / BN)), 512, 0, stream>>>(
      xq, wq, bias, amax, out, M, N, K);
}

// Round 6
// 378.204 us; speedup vs baseline: 1.0792x; 1.0792x over previous
//
#include <hip/hip_runtime.h>

#define FP8_MAX 448.0f
#define EPSF 1e-12f

#define BM 256
#define BN 256
#define BK 64

typedef __attribute__((ext_vector_type(8))) _Float16 half8;
typedef __attribute__((ext_vector_type(4))) float floatx4;

#define VMCNT(n) asm volatile("s_waitcnt vmcnt(" #n ")" ::: "memory")

__device__ inline void async_copy16(const void* gp, void* lp) {
  __builtin_amdgcn_global_load_lds(
      (const __attribute__((address_space(1))) unsigned int*)gp,
      (__attribute__((address_space(3))) unsigned int*)lp,
      16, 0, 0);
}

// -------- fused absmax of two tensors: out[0]=max|a|, out[1]=max|b| -------
__global__ void absmax2_kernel(const float* __restrict__ a, int n4a,
                               const float* __restrict__ b, int n4b,
                               int blocks_a, unsigned* __restrict__ out) {
  const bool isA = (int)blockIdx.x < blocks_a;
  const float4* in4 = (const float4*)(isA ? a : b);
  const int n4 = isA ? n4a : n4b;
  const int nblk = isA ? blocks_a : (gridDim.x - blocks_a);
  const int bid = isA ? blockIdx.x : (blockIdx.x - blocks_a);
  int tid = bid * blockDim.x + threadIdx.x;
  int stride = nblk * blockDim.x;
  float m = 0.f;
  for (int i = tid; i < n4; i += stride) {
    float4 v = in4[i];
    m = fmaxf(m, fmaxf(fmaxf(fabsf(v.x), fabsf(v.y)),
                       fmaxf(fabsf(v.z), fabsf(v.w))));
  }
  for (int off = 32; off > 0; off >>= 1)
    m = fmaxf(m, __shfl_down(m, off, 64));
  __shared__ float smax[4];
  int lane = threadIdx.x & 63, w = threadIdx.x >> 6;
  if (lane == 0) smax[w] = m;
  __syncthreads();
  if (threadIdx.x == 0) {
    float bm = fmaxf(fmaxf(smax[0], smax[1]), fmaxf(smax[2], smax[3]));
    atomicMax(out + (isA ? 0 : 1), __float_as_uint(bm));
  }
}

// -------- fused quantize of two tensors: fp32 -> fp16 ints in [-448,448] --
__global__ void quant2_kernel(const float* __restrict__ a, int n8a,
                              const float* __restrict__ b, int n8b,
                              int blocks_a, _Float16* __restrict__ qa,
                              _Float16* __restrict__ qb,
                              const unsigned* __restrict__ amax_bits) {
  const bool isA = (int)blockIdx.x < blocks_a;
  const float4* in4 = (const float4*)(isA ? a : b);
  half8* out8 = (half8*)(isA ? qa : qb);
  const int n8 = isA ? n8a : n8b;
  const int nblk = isA ? blocks_a : (gridDim.x - blocks_a);
  const int bid = isA ? blockIdx.x : (blockIdx.x - blocks_a);
  const float scale =
      fmaxf(__uint_as_float(amax_bits[isA ? 0 : 1]) / FP8_MAX, EPSF);
  int tid = bid * blockDim.x + threadIdx.x;
  int stride = nblk * blockDim.x;
  for (int i = tid; i < n8; i += stride) {
    float4 va = in4[2 * i], vb = in4[2 * i + 1];
    half8 h;
    h[0] = (_Float16)rintf(fminf(fmaxf(va.x / scale, -FP8_MAX), FP8_MAX));
    h[1] = (_Float16)rintf(fminf(fmaxf(va.y / scale, -FP8_MAX), FP8_MAX));
    h[2] = (_Float16)rintf(fminf(fmaxf(va.z / scale, -FP8_MAX), FP8_MAX));
    h[3] = (_Float16)rintf(fminf(fmaxf(va.w / scale, -FP8_MAX), FP8_MAX));
    h[4] = (_Float16)rintf(fminf(fmaxf(vb.x / scale, -FP8_MAX), FP8_MAX));
    h[5] = (_Float16)rintf(fminf(fmaxf(vb.y / scale, -FP8_MAX), FP8_MAX));
    h[6] = (_Float16)rintf(fminf(fmaxf(vb.z / scale, -FP8_MAX), FP8_MAX));
    h[7] = (_Float16)rintf(fminf(fmaxf(vb.w / scale, -FP8_MAX), FP8_MAX));
    out8[i] = h;
  }
}

// -------- 256x256 4-phase/K-tile NT GEMM (R4 structure, compiler-scheduled
// LDS waits). Reads front-loaded 12/12/0/0; NO manual lgkmcnt drain — the
// compiler emits per-MFMA counted lgkmcnt(N), so the DS drain overlaps the
// MFMA cluster (m97 finding). Safety: every phase's reads are consumed by
// same-phase MFMAs before the phase-end barrier; VMCNT asm "memory" clobber
// fences tile-boundary reads; global_load_lds staging can't hoist above
// barriers (side-effectful intrinsics stay ordered).
__global__ __launch_bounds__(512, 2) void gemm8_kernel(
    const _Float16* __restrict__ A,  // [M][K]
    const _Float16* __restrict__ B,  // [N][K]
    const float* __restrict__ bias, const unsigned* __restrict__ amax,
    float* __restrict__ C,  // [M][N]
    int M, int N, int K) {
  __shared__ __align__(16) _Float16 As[2][BM * BK];
  __shared__ __align__(16) _Float16 Bs[2][BN * BK];

  const int tid = threadIdx.x;
  const int w = tid >> 6;
  const int lane = tid & 63;
  const int wr = w >> 2;  // 0..1
  const int wc = w & 3;   // 0..3

  // XCD-aware block swizzle (gridDim.x divisible by 8)
  const int nwg = gridDim.x;
  const int cpx = nwg >> 3;
  const int swz = (blockIdx.x & 7) * cpx + (blockIdx.x >> 3);
  const int nbn = N / BN;
  const int bm = swz / nbn;
  const int bn = swz % nbn;

  const _Float16* Ab = A + (size_t)bm * BM * K;
  const _Float16* Bb = B + (size_t)bn * BN * K;

  // staging: lane l covers LDS row +(l>>3), LDS granule l&7; fetch DATA
  // granule (l&7)^((l>>3)&7) so reader-side XOR sees linear data.
  const int srow8 = w * 8 + (lane >> 3);
  const int gd8 = ((lane & 7) ^ ((lane >> 3) & 7)) * 8;
  const _Float16* Ag = Ab + (size_t)srow8 * K + gd8;
  const _Float16* Bg = Bb + (size_t)srow8 * K + gd8;

  auto stageA = [&](int kt, int h) {  // half h: rows h*128..h*128+127
#pragma unroll
    for (int r = 2 * h; r < 2 * h + 2; ++r)
      async_copy16(Ag + (size_t)(r * 64) * K + kt * BK,
                   (void*)&As[kt & 1][(r * 64 + w * 8) * BK]);
  };
  auto stageB = [&](int kt, int h) {
#pragma unroll
    for (int r = 2 * h; r < 2 * h + 2; ++r)
      async_copy16(Bg + (size_t)(r * 64) * K + kt * BK,
                   (void*)&Bs[kt & 1][(r * 64 + w * 8) * BK]);
  };

  // swizzled ds_read geometry: row = base16 + (lane&15), granule kk*4+(lane>>4)
  const int lr = lane & 15;
  const int hi = lane >> 4;
  const int aoff = (wr * 128 + lr) * BK;
  const int boff = (wc * 64 + lr) * BK;
  const int g0 = (hi ^ (lr & 7)) * 8;        // kk0
  const int g1 = ((4 + hi) ^ (lr & 7)) * 8;  // kk1

  half8 aL[4][2], aH[4][2], bL[2][2], bH[2][2];
  floatx4 acc[8][4] = {};
  const int nt = K / BK;

  // ---- prologue: tile0 all 4 halves + tile1 A-halves; vmcnt(4) leaves
  // exactly A(1,h0/h1) in flight == steady-state invariant.
  stageA(0, 0); stageA(0, 1); stageB(0, 0); stageB(0, 1);
  stageA(1, 0); stageA(1, 1);
  VMCNT(4);
  __builtin_amdgcn_s_barrier();

  for (int t = 0; t < nt; ++t) {
    const int b = t & 1;
    const _Float16* Asb = &As[b][0];
    const _Float16* Bsb = &Bs[b][0];

    // ============ P0: 12 reads; stage B(t+1,h0); MFMA m0-3 x n0-1
#pragma unroll
    for (int m = 0; m < 4; ++m) {
      aL[m][0] = *(const half8*)&Asb[aoff + m * 16 * BK + g0];
      aL[m][1] = *(const half8*)&Asb[aoff + m * 16 * BK + g1];
    }
#pragma unroll
    for (int n = 0; n < 2; ++n) {
      bL[n][0] = *(const half8*)&Bsb[boff + n * 16 * BK + g0];
      bL[n][1] = *(const half8*)&Bsb[boff + n * 16 * BK + g1];
    }
    if (t + 1 < nt) stageB(t + 1, 0);
    __builtin_amdgcn_s_barrier();
    __builtin_amdgcn_s_setprio(1);
#pragma unroll
    for (int m = 0; m < 4; ++m)
#pragma unroll
      for (int n = 0; n < 2; ++n)
#pragma unroll
        for (int kk = 0; kk < 2; ++kk)
          acc[m][n] = __builtin_amdgcn_mfma_f32_16x16x32_f16(
              aL[m][kk], bL[n][kk], acc[m][n], 0, 0, 0);
    __builtin_amdgcn_s_setprio(0);
    __builtin_amdgcn_s_barrier();

    // ============ P1: 12 reads; stage B(t+1,h1); MFMA m0-3 x n2-3
#pragma unroll
    for (int m = 0; m < 4; ++m) {
      aH[m][0] = *(const half8*)&Asb[aoff + (64 + m * 16) * BK + g0];
      aH[m][1] = *(const half8*)&Asb[aoff + (64 + m * 16) * BK + g1];
    }
#pragma unroll
    for (int n = 0; n < 2; ++n) {
      bH[n][0] = *(const half8*)&Bsb[boff + (32 + n * 16) * BK + g0];
      bH[n][1] = *(const half8*)&Bsb[boff + (32 + n * 16) * BK + g1];
    }
    if (t + 1 < nt) stageB(t + 1, 1);
    __builtin_amdgcn_s_barrier();
    __builtin_amdgcn_s_setprio(1);
#pragma unroll
    for (int m = 0; m < 4; ++m)
#pragma unroll
      for (int n = 0; n < 2; ++n)
#pragma unroll
        for (int kk = 0; kk < 2; ++kk)
          acc[m][2 + n] = __builtin_amdgcn_mfma_f32_16x16x32_f16(
              aL[m][kk], bH[n][kk], acc[m][2 + n], 0, 0, 0);
    __builtin_amdgcn_s_setprio(0);
    __builtin_amdgcn_s_barrier();  // all reads of buf[b] complete & published

    // ============ P2: stage A(t+2,h0) into buf[b]; pure MFMA m4-7 x n0-1
    if (t + 2 < nt) stageA(t + 2, 0);
    __builtin_amdgcn_s_setprio(1);
#pragma unroll
    for (int m = 0; m < 4; ++m)
#pragma unroll
      for (int n = 0; n < 2; ++n)
#pragma unroll
        for (int kk = 0; kk < 2; ++kk)
          acc[4 + m][n] = __builtin_amdgcn_mfma_f32_16x16x32_f16(
              aH[m][kk], bL[n][kk], acc[4 + m][n], 0, 0, 0);
    __builtin_amdgcn_s_setprio(0);
    __builtin_amdgcn_s_barrier();

    // ============ P3: stage A(t+2,h1); pure MFMA m4-7 x n2-3; counted drain
    if (t + 2 < nt) stageA(t + 2, 1);
    __builtin_amdgcn_s_setprio(1);
#pragma unroll
    for (int m = 0; m < 4; ++m)
#pragma unroll
      for (int n = 0; n < 2; ++n)
#pragma unroll
        for (int kk = 0; kk < 2; ++kk)
          acc[4 + m][2 + n] = __builtin_amdgcn_mfma_f32_16x16x32_f16(
              aH[m][kk], bH[n][kk], acc[4 + m][2 + n], 0, 0, 0);
    __builtin_amdgcn_s_setprio(0);
    if (t + 2 < nt) {
      VMCNT(4);  // leave A(t+2) flying; tile t+1 fully resident
    } else {
      VMCNT(0);  // tail: drain everything
    }
    __builtin_amdgcn_s_barrier();
  }

  // ---- epilogue: dequant + bias
  const float sx = fmaxf(__uint_as_float(amax[0]) / FP8_MAX, EPSF);
  const float sw = fmaxf(__uint_as_float(amax[1]) / FP8_MAX, EPSF);
  const float s = sx * sw;

  const int row0 = bm * BM + wr * 128 + hi * 4;  // C/D: col=lane&15,
  const int col0 = bn * BN + wc * 64 + lr;       // row=(lane>>4)*4+reg
  float bv[4];
#pragma unroll
  for (int n = 0; n < 4; ++n) bv[n] = bias[col0 + n * 16];

#pragma unroll
  for (int m = 0; m < 8; ++m) {
#pragma unroll
    for (int n = 0; n < 4; ++n) {
      const size_t base = (size_t)(row0 + m * 16) * N + col0 + n * 16;
#pragma unroll
      for (int r = 0; r < 4; ++r)
        C[base + (size_t)r * N] = acc[m][n][r] * s + bv[n];
    }
  }
}

extern "C" void kernel_launch(void* const* d_in, const int* in_sizes, int n_in,
                              void* d_out, int out_size, void* d_ws,
                              size_t ws_size, hipStream_t stream) {
  const float* x = (const float*)d_in[0];
  const float* wgt = (const float*)d_in[1];
  const float* bias = (const float*)d_in[2];
  float* out = (float*)d_out;

  const int N = in_sizes[2];      // out features (4096)
  const int K = in_sizes[1] / N;  // in features (4096)
  const int M = in_sizes[0] / K;  // rows (8192)

  unsigned* amax = (unsigned*)d_ws;
  _Float16* xq = (_Float16*)((char*)d_ws + 256);
  _Float16* wq =
      (_Float16*)((char*)d_ws + 256 + (size_t)M * K * sizeof(_Float16));

  hipMemsetAsync(d_ws, 0, 8, stream);
  absmax2_kernel<<<3072, 256, 0, stream>>>(x, M * K / 4, wgt, N * K / 4, 2048,
                                           amax);
  quant2_kernel<<<3072, 256, 0, stream>>>(x, M * K / 8, wgt, N * K / 8, 2048,
                                          xq, wq, amax);

  gemm8_kernel<<<dim3((M / BM) * (N / BN)), 512, 0, stream>>>(
      xq, wq, bias, amax, out, M, N, K);
}